// Round 1
// baseline (4952.480 us; speedup 1.0000x reference)
//
#include <hip/hip_runtime.h>

#define NROWS 65536
#define DIM   512
#define INV_N (1.0f/65536.0f)
#define INV_TEMP 0.1f
#define T_ITERS 10

// ---------------------------------------------------------------------------
// colsum partials: part[ch][c] = sum of in[ch*1024 .. +1024)[, c]
__global__ __launch_bounds__(256) void colsum_part_k(const float* __restrict__ in,
                                                     float* __restrict__ part) {
    int ch = blockIdx.x;            // 64 chunks of 1024 rows
    int t  = threadIdx.x;           // 256 threads, 2 cols each
    int c  = 2 * t;
    const float* p = in + (size_t)ch * 1024 * DIM + c;
    float s0 = 0.f, s1 = 0.f;
    for (int r = 0; r < 1024; ++r) {
        float2 v = *reinterpret_cast<const float2*>(p + (size_t)r * DIM);
        s0 += v.x; s1 += v.y;
    }
    part[ch * DIM + c]     = s0;
    part[ch * DIM + c + 1] = s1;
}

// ---------------------------------------------------------------------------
// Gram split-K partials: gp[z] += in_chunk^T @ in_chunk  (chunk = 4096 rows)
// grid (8,8,16), block 256; 64x64 tile per WG, 4x4 per thread.
__global__ __launch_bounds__(256) void gram_k(const float* __restrict__ in,
                                              float* __restrict__ gp) {
    __shared__ float As[16][68];
    __shared__ float Bs[16][68];
    int ci0 = blockIdx.x * 64, cj0 = blockIdx.y * 64;
    int z = blockIdx.z;
    int t = threadIdx.x;
    int tx = t & 15, ty = t >> 4;
    int lr = t >> 4;          // 0..15 staged row
    int lc = (t & 15) * 4;    // staged col quad
    float acc[4][4] = {};
    const float* baseA = in + (size_t)z * 4096 * DIM;
    const float* pa = baseA + (size_t)lr * DIM + ci0 + lc;
    const float* pb = baseA + (size_t)lr * DIM + cj0 + lc;
    float4 a = *reinterpret_cast<const float4*>(pa);
    float4 b = *reinterpret_cast<const float4*>(pb);
    for (int k0 = 0; k0 < 4096; k0 += 16) {
        __syncthreads();
        *reinterpret_cast<float4*>(&As[lr][lc]) = a;
        *reinterpret_cast<float4*>(&Bs[lr][lc]) = b;
        __syncthreads();
        if (k0 + 16 < 4096) {
            a = *reinterpret_cast<const float4*>(pa + (size_t)(k0 + 16) * DIM);
            b = *reinterpret_cast<const float4*>(pb + (size_t)(k0 + 16) * DIM);
        }
#pragma unroll
        for (int k = 0; k < 16; ++k) {
            float4 av = *reinterpret_cast<const float4*>(&As[k][4 * ty]);
            float4 bv = *reinterpret_cast<const float4*>(&Bs[k][4 * tx]);
            float aa[4] = {av.x, av.y, av.z, av.w};
            float bb[4] = {bv.x, bv.y, bv.z, bv.w};
#pragma unroll
            for (int i = 0; i < 4; ++i)
#pragma unroll
                for (int j = 0; j < 4; ++j)
                    acc[i][j] = fmaf(aa[i], bb[j], acc[i][j]);
        }
    }
    float* o = gp + (size_t)z * DIM * DIM;
#pragma unroll
    for (int i = 0; i < 4; ++i) {
        float4 v = {acc[i][0], acc[i][1], acc[i][2], acc[i][3]};
        *reinterpret_cast<float4*>(o + (size_t)(ci0 + 4 * ty + i) * DIM + cj0 + 4 * tx) = v;
    }
}

// Reduce 16 split-K partials -> G
__global__ __launch_bounds__(256) void gram_reduce_k(const float* __restrict__ gp,
                                                     float* __restrict__ G) {
    int idx = (blockIdx.x * 256 + threadIdx.x) * 4;   // grid 256
    float4 s = {0.f, 0.f, 0.f, 0.f};
    for (int ch = 0; ch < 16; ++ch) {
        float4 v = *reinterpret_cast<const float4*>(gp + (size_t)ch * DIM * DIM + idx);
        s.x += v.x; s.y += v.y; s.z += v.z; s.w += v.w;
    }
    *reinterpret_cast<float4*>(G + idx) = s;
}

// ---------------------------------------------------------------------------
// mh[c] = (1/n) * sum_k colsum[k] * W[k][c]
__global__ __launch_bounds__(256) void meanh_k(const float* __restrict__ part,
                                               const float* __restrict__ W,
                                               float* __restrict__ mh) {
    __shared__ float cs[DIM];
    int t = threadIdx.x;
    for (int c = t; c < DIM; c += 256) {
        float s = 0.f;
        for (int ch = 0; ch < 64; ++ch) s += part[ch * DIM + c];
        cs[c] = s;
    }
    __syncthreads();
    for (int c = t; c < DIM; c += 256) {
        float s = 0.f;
        for (int k = 0; k < DIM; ++k) s = fmaf(cs[k], W[(size_t)k * DIM + c], s);
        mh[c] = s * INV_N;
    }
}

// ---------------------------------------------------------------------------
// Generic 512x512x512 fp32 GEMM. 32x32 tile/WG (grid 16x16), 2x2 per thread.
// mode 0: C = op(A)@B ; mode 1: C = 1.5C - 0.5*A@B ; mode 2: C = (A@B)*scal[sidx]
__device__ __forceinline__ void small_gemm_body(const float* __restrict__ A, int ta,
                                                const float* __restrict__ B,
                                                float* __restrict__ C, int mode,
                                                const float* __restrict__ scal, int sidx,
                                                int bx, int by) {
    __shared__ float As[32][36];   // [k][m]
    __shared__ float Bs[32][36];   // [k][n]
    int m0 = bx * 32, n0 = by * 32;
    int t = threadIdx.x;
    int tx = t & 15, ty = t >> 4;
    int lr = t >> 3;          // 0..31
    int lc = (t & 7) * 4;     // 0..28
    float acc[2][2] = {};
    float4 av, bv;
    if (ta) av = *reinterpret_cast<const float4*>(A + (size_t)lr * DIM + m0 + lc);
    else    av = *reinterpret_cast<const float4*>(A + (size_t)(m0 + lr) * DIM + lc);
    bv = *reinterpret_cast<const float4*>(B + (size_t)lr * DIM + n0 + lc);
    for (int k0 = 0; k0 < DIM; k0 += 32) {
        __syncthreads();
        if (ta) {
            *reinterpret_cast<float4*>(&As[lr][lc]) = av;
        } else {
            As[lc + 0][lr] = av.x; As[lc + 1][lr] = av.y;
            As[lc + 2][lr] = av.z; As[lc + 3][lr] = av.w;
        }
        *reinterpret_cast<float4*>(&Bs[lr][lc]) = bv;
        __syncthreads();
        if (k0 + 32 < DIM) {
            if (ta) av = *reinterpret_cast<const float4*>(A + (size_t)(k0 + 32 + lr) * DIM + m0 + lc);
            else    av = *reinterpret_cast<const float4*>(A + (size_t)(m0 + lr) * DIM + k0 + 32 + lc);
            bv = *reinterpret_cast<const float4*>(B + (size_t)(k0 + 32 + lr) * DIM + n0 + lc);
        }
#pragma unroll
        for (int k = 0; k < 32; ++k) {
            float a0 = As[k][2 * ty], a1 = As[k][2 * ty + 1];
            float b0 = Bs[k][2 * tx], b1 = Bs[k][2 * tx + 1];
            acc[0][0] = fmaf(a0, b0, acc[0][0]);
            acc[0][1] = fmaf(a0, b1, acc[0][1]);
            acc[1][0] = fmaf(a1, b0, acc[1][0]);
            acc[1][1] = fmaf(a1, b1, acc[1][1]);
        }
    }
    int m = m0 + 2 * ty, nn = n0 + 2 * tx;
    size_t i00 = (size_t)m * DIM + nn, i10 = (size_t)(m + 1) * DIM + nn;
    if (mode == 0) {
        C[i00] = acc[0][0]; C[i00 + 1] = acc[0][1];
        C[i10] = acc[1][0]; C[i10 + 1] = acc[1][1];
    } else if (mode == 1) {
        C[i00]     = 1.5f * C[i00]     - 0.5f * acc[0][0];
        C[i00 + 1] = 1.5f * C[i00 + 1] - 0.5f * acc[0][1];
        C[i10]     = 1.5f * C[i10]     - 0.5f * acc[1][0];
        C[i10 + 1] = 1.5f * C[i10 + 1] - 0.5f * acc[1][1];
    } else {
        float s = scal[sidx];
        C[i00] = acc[0][0] * s; C[i00 + 1] = acc[0][1] * s;
        C[i10] = acc[1][0] * s; C[i10 + 1] = acc[1][1] * s;
    }
}

__global__ __launch_bounds__(256) void small_gemm_k(const float* __restrict__ A, int ta,
                                                    const float* __restrict__ B,
                                                    float* __restrict__ C, int mode,
                                                    const float* __restrict__ scal, int sidx) {
    small_gemm_body(A, ta, B, C, mode, scal, sidx, blockIdx.x, blockIdx.y);
}

// batched NS products: z=0: T1 = P@P ; z=1: T2 = P@S
__global__ __launch_bounds__(256) void ns_tt_k(const float* __restrict__ P,
                                               const float* __restrict__ S,
                                               float* __restrict__ T1,
                                               float* __restrict__ T2) {
    if (blockIdx.z == 0) small_gemm_body(P, 0, P, T1, 0, nullptr, 0, blockIdx.x, blockIdx.y);
    else                 small_gemm_body(P, 0, S, T2, 0, nullptr, 0, blockIdx.x, blockIdx.y);
}

// ---------------------------------------------------------------------------
// trace of cov; writes scal[0]=1/tr, scal[1]=1/sqrt(tr)
__global__ __launch_bounds__(256) void trace_k(const float* __restrict__ covh,
                                               const float* __restrict__ mh,
                                               float* __restrict__ scal) {
    __shared__ float red[256];
    int t = threadIdx.x;
    float s = 0.f;
    for (int i = t; i < DIM; i += 256)
        s += covh[(size_t)i * DIM + i] * INV_N - mh[i] * mh[i] + INV_TEMP;
    red[t] = s;
    __syncthreads();
    for (int o = 128; o > 0; o >>= 1) {
        if (t < o) red[t] += red[t + o];
        __syncthreads();
    }
    if (t == 0) {
        float tr = red[0];
        scal[0] = 1.0f / tr;
        scal[1] = 1.0f / sqrtf(tr);
    }
}

// S = (covh/n - mh mh^T + I/temp) / tr
__global__ __launch_bounds__(256) void makeS_k(const float* __restrict__ covh,
                                               const float* __restrict__ mh,
                                               const float* __restrict__ scal,
                                               float* __restrict__ S) {
    int idx = blockIdx.x * 256 + threadIdx.x;   // grid 1024
    int i = idx >> 9, j = idx & 511;
    float v = covh[idx] * INV_N - mh[i] * mh[j] + ((i == j) ? INV_TEMP : 0.f);
    S[idx] = v * scal[0];
}

__global__ __launch_bounds__(256) void initP_k(float* __restrict__ P) {
    int idx = blockIdx.x * 256 + threadIdx.x;   // grid 1024
    int i = idx >> 9, j = idx & 511;
    P[idx] = (i == j) ? 1.0f : 0.f;
}

// bias[c] = (1/sqrt(tr)) * sum_k mh[k] * P[k][c]
__global__ __launch_bounds__(256) void bias_k(const float* __restrict__ mh,
                                              const float* __restrict__ P,
                                              const float* __restrict__ scal,
                                              float* __restrict__ bias) {
    __shared__ float m_s[DIM];
    int t = threadIdx.x;
    for (int c = t; c < DIM; c += 256) m_s[c] = mh[c];
    __syncthreads();
    float ist = scal[1];
    for (int c = t; c < DIM; c += 256) {
        float s = 0.f;
        for (int k = 0; k < DIM; ++k) s = fmaf(m_s[k], P[(size_t)k * DIM + c], s);
        bias[c] = s * ist;
    }
}

// ---------------------------------------------------------------------------
// OUT[N x D] = IN @ WC - bias.  grid (8, 1024) = (colTile, rowTile), block 256.
__global__ __launch_bounds__(256) void out_gemm_k(const float* __restrict__ in,
                                                  const float* __restrict__ WC,
                                                  const float* __restrict__ bias,
                                                  float* __restrict__ out) {
    __shared__ float As[16][68];   // [k][m]
    __shared__ float Bs[16][68];   // [k][n]
    int n0 = blockIdx.x * 64, m0 = blockIdx.y * 64;
    int t = threadIdx.x;
    int tx = t & 15, ty = t >> 4;
    int ar = t >> 2;          // 0..63 row
    int ac = (t & 3) * 4;     // 0..12 k-quad
    int br = t >> 4;          // 0..15 k row
    int bc = (t & 15) * 4;    // col quad
    float acc[4][4] = {};
    const float* pa = in + (size_t)(m0 + ar) * DIM + ac;
    const float* pb = WC + (size_t)br * DIM + n0 + bc;
    float4 a = *reinterpret_cast<const float4*>(pa);
    float4 b = *reinterpret_cast<const float4*>(pb);
    for (int k0 = 0; k0 < DIM; k0 += 16) {
        __syncthreads();
        As[ac + 0][ar] = a.x; As[ac + 1][ar] = a.y;
        As[ac + 2][ar] = a.z; As[ac + 3][ar] = a.w;
        *reinterpret_cast<float4*>(&Bs[br][bc]) = b;
        __syncthreads();
        if (k0 + 16 < DIM) {
            a = *reinterpret_cast<const float4*>(pa + k0 + 16);
            b = *reinterpret_cast<const float4*>(pb + (size_t)(k0 + 16) * DIM);
        }
#pragma unroll
        for (int k = 0; k < 16; ++k) {
            float4 av = *reinterpret_cast<const float4*>(&As[k][4 * ty]);
            float4 bv = *reinterpret_cast<const float4*>(&Bs[k][4 * tx]);
            float aa[4] = {av.x, av.y, av.z, av.w};
            float bb[4] = {bv.x, bv.y, bv.z, bv.w};
#pragma unroll
            for (int i = 0; i < 4; ++i)
#pragma unroll
                for (int j = 0; j < 4; ++j)
                    acc[i][j] = fmaf(aa[i], bb[j], acc[i][j]);
        }
    }
    float4 bvv = *reinterpret_cast<const float4*>(bias + n0 + 4 * tx);
    float bb[4] = {bvv.x, bvv.y, bvv.z, bvv.w};
#pragma unroll
    for (int i = 0; i < 4; ++i) {
        float4 v = {acc[i][0] - bb[0], acc[i][1] - bb[1],
                    acc[i][2] - bb[2], acc[i][3] - bb[3]};
        *reinterpret_cast<float4*>(out + (size_t)(m0 + 4 * ty + i) * DIM + n0 + 4 * tx) = v;
    }
}

// ---------------------------------------------------------------------------
extern "C" void kernel_launch(void* const* d_in, const int* in_sizes, int n_in,
                              void* d_out, int out_size, void* d_ws, size_t ws_size,
                              hipStream_t stream) {
    const float* x = (const float*)d_in[0];
    const float* Wl[3] = {(const float*)d_in[1], (const float*)d_in[2], (const float*)d_in[3]};
    float* out = (float*)d_out;
    float* ws  = (float*)d_ws;

    const size_t MM = (size_t)DIM * DIM;
    float* G     = ws;
    float* S     = G + MM;
    float* P     = S + MM;
    float* T1    = P + MM;
    float* T2    = T1 + MM;
    float* covh  = T2 + MM;
    float* WC    = covh + MM;
    float* gramp = WC + MM;             // 16 * MM
    float* cpart = gramp + 16 * MM;     // 64 * DIM
    float* mh    = cpart + 64 * DIM;
    float* bias  = mh + DIM;
    float* scal  = bias + DIM;          // [0]=1/tr, [1]=1/sqrt(tr)

    for (int l = 0; l < 3; ++l) {
        const float* in = (l == 0) ? x : out + (size_t)(l - 1) * NROWS * DIM;
        const float* W  = Wl[l];
        float* o = out + (size_t)l * NROWS * DIM;

        colsum_part_k<<<64, 256, 0, stream>>>(in, cpart);
        gram_k<<<dim3(8, 8, 16), 256, 0, stream>>>(in, gramp);
        gram_reduce_k<<<256, 256, 0, stream>>>(gramp, G);
        meanh_k<<<1, 256, 0, stream>>>(cpart, W, mh);
        // covh = W^T @ (G @ W)
        small_gemm_k<<<dim3(16, 16), 256, 0, stream>>>(G, 0, W, T1, 0, nullptr, 0);
        small_gemm_k<<<dim3(16, 16), 256, 0, stream>>>(W, 1, T1, covh, 0, nullptr, 0);
        trace_k<<<1, 256, 0, stream>>>(covh, mh, scal);
        makeS_k<<<1024, 256, 0, stream>>>(covh, mh, scal, S);
        initP_k<<<1024, 256, 0, stream>>>(P);
        for (int it = 0; it < T_ITERS; ++it) {
            ns_tt_k<<<dim3(16, 16, 2), 256, 0, stream>>>(P, S, T1, T2);
            small_gemm_k<<<dim3(16, 16), 256, 0, stream>>>(T1, 0, T2, P, 1, nullptr, 0);
        }
        // WC = W @ P * (1/sqrt(tr));  bias = mh @ P * (1/sqrt(tr))
        small_gemm_k<<<dim3(16, 16), 256, 0, stream>>>(W, 0, P, WC, 2, scal, 1);
        bias_k<<<1, 256, 0, stream>>>(mh, P, scal, bias);
        out_gemm_k<<<dim3(8, 1024), 256, 0, stream>>>(in, WC, bias, o);
    }
}